// Round 7
// baseline (270.722 us; speedup 1.0000x reference)
//
#include <hip/hip_runtime.h>
#include <hip/hip_bf16.h>
#include <math.h>

// Problem constants
#define BB     512
#define INF    256
#define CONDF  128
#define NEXP   8
#define HDIM   64
#define TPE    49280      // IN*DP + IN*DN + DN
#define TOTC   394240     // N*TPE
#define NSPLIT 16
#define CW     1536       // GEMM columns: 8 experts * (64 wp + 128 wn)
#define KB     261        // K blocks of 64: 64*4 main + 5 tail (16704 total K)

// Workspace layout (bytes). Total ~76.9 MB.
#define XB_OFF  0u                    // ushort [512][256] = 262144  (x bf16)
#define HBR_OFF 262144u               // ushort [512][64]  = 65536   (h bf16)
#define GW_OFF  327680u               // float  [512][8]
#define CB_OFF  344064u               // float  [1536]
#define BT_OFF  352256u               // ushort [261][1536][64] = 51,314,688
#define P_OFF   51666944u             // ushort [16][512][1536] = 25,165,824 (bf16 partials)

typedef __bf16          bf16x8 __attribute__((ext_vector_type(8)));
typedef unsigned short  us8    __attribute__((ext_vector_type(8)));
typedef float           f32x4  __attribute__((ext_vector_type(4)));

__device__ __forceinline__ unsigned short f2bf(float f) {
  unsigned u = __builtin_bit_cast(unsigned, f);
  u += 0x7fffu + ((u >> 16) & 1u);           // RNE
  return (unsigned short)(u >> 16);
}
__device__ __forceinline__ float bf2f(unsigned short u) {
  return __builtin_bit_cast(float, ((unsigned)u) << 16);
}

__device__ __forceinline__ void gld16(const void* g, const void* l) {
  __builtin_amdgcn_global_load_lds(
      (const __attribute__((address_space(1))) unsigned int*)g,
      (__attribute__((address_space(3))) unsigned int*)l, 16, 0, 0);
}

// packed bf16 scale: o[j] = bf16(x[j] * h)  (4x __hmul2)
__device__ __forceinline__ us8 scale8(us8 xo, unsigned short hb) {
  union HU { unsigned short u; __hip_bfloat16 b; } hu; hu.u = hb;
  __hip_bfloat162 h2; h2.x = hu.b; h2.y = hu.b;
  union VU { us8 u; __hip_bfloat162 h[4]; } a, o;
  a.u = xo;
#pragma unroll
  for (int j = 0; j < 4; ++j) o.h[j] = __hmul2(a.h[j], h2);
  return o.u;
}

// ---------------- K2 (merged): blocks 0..1535 = Bt transpose + tail + colbias;
//                 blocks 1536..2047 = per-sample prep (x/h bf16, softmax gates).
// Bt[kb][c][ko] bf16, kb = t*4+ib, c = ne*192+r. One transpose block per (t, ne, sec).
// LDS transpose with octet XOR swizzle:
//   element (p, i) stored at Ls[p*256 + ((i&7) | (((i>>3) ^ (p&31)) << 3))]
__global__ void k_bt(const float* __restrict__ hW2, unsigned short* __restrict__ Bt,
                     const float* __restrict__ bwp, const float* __restrict__ bwn,
                     const float* __restrict__ bbn, const float* __restrict__ hb2,
                     float* __restrict__ colbias,
                     const float* __restrict__ x, const float* __restrict__ cond,
                     const float* __restrict__ hW1, const float* __restrict__ hb1,
                     const float* __restrict__ gW1, const float* __restrict__ gb1,
                     const float* __restrict__ gW2, const float* __restrict__ gb2,
                     unsigned short* __restrict__ Xb, unsigned short* __restrict__ Hbr,
                     float* __restrict__ gw) {
  const int bx = blockIdx.x;
  const int tid = threadIdx.x;          // 256

  if (bx >= 1536) {                     // ---- prep path
    const int b = bx - 1536;
    __shared__ float xs[INF], cs[CONDF], hs[HDIM], g1[24], ls[8], es[8];
    xs[tid] = x[b * INF + tid];
    if (tid < CONDF) cs[tid] = cond[b * CONDF + tid];
    __syncthreads();
    if (tid < HDIM) {
      float acc = hb1[tid];
      for (int q = 0; q < CONDF; ++q) acc = fmaf(cs[q], hW1[q * HDIM + tid], acc);
      hs[tid] = fmaxf(acc, 0.f);
    }
    if (tid >= 64 && tid < 88) {
      const int r = tid - 64;
      float acc = gb1[r];
      for (int q = 0; q < CONDF; ++q) acc = fmaf(cs[q], gW1[q * 24 + r], acc);
      g1[r] = fmaxf(acc, 0.f);
    }
    __syncthreads();
    if (tid < NEXP) {
      float acc = gb2[tid];
      for (int j = 0; j < 24; ++j) acc = fmaf(g1[j], gW2[j * NEXP + tid], acc);
      ls[tid] = acc;
    }
    __syncthreads();
    if (tid < NEXP) {
      float m = ls[0];
      for (int j = 1; j < NEXP; ++j) m = fmaxf(m, ls[j]);
      es[tid] = expf(ls[tid] - m);
    }
    __syncthreads();
    if (tid < NEXP) {
      float s = 0.f;
      for (int j = 0; j < NEXP; ++j) s += es[j];
      gw[b * NEXP + tid] = es[tid] / s;
    }
    Xb[b * INF + tid] = f2bf(xs[tid]);
    if (tid < HDIM) Hbr[b * HDIM + tid] = f2bf(hs[tid]);
    return;
  }

  // ---- Bt transpose path
  const int t = bx / 24, rem = bx % 24, ne = rem / 3, sec = rem % 3;
  const size_t base = (size_t)t * TOTC + (size_t)ne * TPE + (sec ? 16384 : 0);
  const int dst  = sec ? 128 : 64;
  const int poff = (sec == 2) ? 64 : 0;
  const int cbase = ne * 192 + (sec == 0 ? 0 : (sec == 1 ? 64 : 128));
  __shared__ __align__(16) unsigned short Ls[64 * 256];   // [p][i-swizzled]
#pragma unroll
  for (int it = 0; it < 16; ++it) {
    const int f = it * 256 + tid;       // 4096 float4s: i = f>>4 in 0..255, p4 = (f&15)*4
    const int i = f >> 4, p4 = (f & 15) * 4;
    const int e = i >> 3, q = i & 7;
    f32x4 v = *(const f32x4*)(hW2 + base + (size_t)i * dst + poff + p4);
#pragma unroll
    for (int j = 0; j < 4; ++j) {
      const int p = p4 + j;
      Ls[(p << 8) + (((e ^ (p & 31)) << 3) | q)] = f2bf(v[j]);
    }
  }
  // merged tail rows (threads 0-63, c2 = bx): kb 256..260 = base weights/hb2/bias rows
  if (tid < 64) {
    const int c2 = bx, ne2 = c2 / 192, r2 = c2 % 192;
#pragma unroll
    for (int kb = 0; kb < 5; ++kb) {
      const int j = kb * 64 + tid;      // 0..320
      float v;
      if (j < 256) {
        const int i = j;
        if (r2 < 64) v = bwp[(ne2 * INF + i) * 64 + r2] + hb2[(size_t)ne2 * TPE + i * 64 + r2];
        else         v = bwn[(ne2 * INF + i) * 128 + (r2 - 64)] + hb2[(size_t)ne2 * TPE + 16384 + i * 128 + (r2 - 64)];
      } else {
        const int t2 = j - 256;
        v = (r2 < 64) ? 0.f : hW2[(size_t)t2 * TOTC + (size_t)ne2 * TPE + 49152 + (r2 - 64)];
      }
      Bt[((size_t)(256 + kb) * CW + c2) * 64 + tid] = f2bf(v);
    }
    if (tid == 0)
      colbias[c2] = (r2 < 64) ? 0.f
                  : bbn[ne2 * 128 + (r2 - 64)] + hb2[(size_t)ne2 * TPE + 49152 + (r2 - 64)];
  }
  __syncthreads();
#pragma unroll
  for (int it2 = 0; it2 < 8; ++it2) {
    const int of = it2 * 256 + tid;     // 2048 us8 outputs
    const int p = of >> 5, seg = of & 31, ib = seg >> 3, k8 = seg & 7;
    us8 o = *(const us8*)(&Ls[(p << 8) + ((seg ^ (p & 31)) << 3)]);
    *(us8*)(Bt + ((size_t)(t * 4 + ib) * CW + cbase + p) * 64 + k8 * 8) = o;
  }
}

// ---------------- K3: split-K MFMA GEMM. Block 128m x 128n, 768 blocks = 3/CU.
// XCD co-location swizzle (4 m-blocks of a (nt,s) group share an XCD).
// A built IN-REGISTER: af = bf16(h[row])*x-octet (rank-1 structure); only B staged
// through LDS (global_load_lds w16, XOR swizzle). Tail kbs 256..260: raw x/h, h=1.
__launch_bounds__(256, 3)
__global__ void k_gemm(const unsigned short* __restrict__ Xb,
                       const unsigned short* __restrict__ Hbr,
                       const unsigned short* __restrict__ Bt,
                       unsigned short* __restrict__ P) {
  const int bid = blockIdx.x;           // 0..767
  const int g  = (bid >> 5) * 8 + (bid & 7);
  const int mt = (bid >> 3) & 3;
  const int nt = g >> 4;                // 0..11
  const int s  = g & 15;                // 0..15
  const int m0 = mt * 128, n0 = nt * 128;
  // balanced split-K: first 5 splits take 17 kbs, rest 16  (5*17 + 11*16 = 261)
  const int kb0 = s * 16 + (s < 5 ? s : 5);
  const int kb1 = kb0 + 16 + (s < 5 ? 1 : 0);
  const int tid = threadIdx.x;
  __shared__ __align__(16) unsigned short Bs[128 * 64];

  f32x4 acc[4][4];
#pragma unroll
  for (int mi = 0; mi < 4; ++mi)
#pragma unroll
    for (int ni = 0; ni < 4; ++ni) acc[mi][ni] = (f32x4){0.f, 0.f, 0.f, 0.f};

  const int wv = tid >> 6, lane = tid & 63;
  const int wm = wv >> 1, wn = wv & 1;
  const int lrow = lane & 15, quad = lane >> 4;
  const int srow = tid >> 3;            // 0..31
  const int sg0  = tid & 7;
  const int arow = m0 + wm * 64 + lrow; // + mi*16

  const unsigned short* bb = Bt + ((size_t)kb0 * CW + n0) * 64;

  for (int kb = kb0; kb < kb1; ++kb) {
    // stage B tile (128n x 64k) via global_load_lds
#pragma unroll
    for (int it = 0; it < 4; ++it) {
      const int r = it * 32 + srow;
      const int ga = sg0 ^ (r & 7);
      const int ldsoff = __builtin_amdgcn_readfirstlane(it * 4096 + wv * 1024);
      gld16(bb + (size_t)r * 64 + ga * 8, (const char*)Bs + ldsoff);
    }
    // build A fragments in-register (overlaps the staging drain)
    bf16x8 af[2][4];
    {
      const bool main_kb = (kb < 256);
      const unsigned short* asrc = (kb < 260) ? (Xb + (kb & 3) * 64) : Hbr;
      const int astr = (kb < 260) ? INF : HDIM;
      const int t = kb >> 2;
#pragma unroll
      for (int mi = 0; mi < 4; ++mi) {
        const int row = arow + mi * 16;
        us8 xo0 = *(const us8*)(asrc + (size_t)row * astr + quad * 8);
        us8 xo1 = *(const us8*)(asrc + (size_t)row * astr + 32 + quad * 8);
        if (main_kb) {
          const unsigned short hb = Hbr[row * HDIM + t];
          xo0 = scale8(xo0, hb);
          xo1 = scale8(xo1, hb);
        }
        af[0][mi] = *(bf16x8*)&xo0;
        af[1][mi] = *(bf16x8*)&xo1;
      }
    }
    __syncthreads();
#pragma unroll
    for (int kh = 0; kh < 2; ++kh) {
      bf16x8 bfr[4];
#pragma unroll
      for (int ni = 0; ni < 4; ++ni) {
        const int r = wn * 64 + ni * 16 + lrow;
        const int ga = (kh * 4 + quad) ^ (r & 7);
        bfr[ni] = *(const bf16x8*)(Bs + r * 64 + ga * 8);
      }
#pragma unroll
      for (int mi = 0; mi < 4; ++mi)
#pragma unroll
        for (int ni = 0; ni < 4; ++ni)
          acc[mi][ni] = __builtin_amdgcn_mfma_f32_16x16x32_bf16(af[kh][mi], bfr[ni], acc[mi][ni], 0, 0, 0);
    }
    __syncthreads();
    bb += (size_t)CW * 64;
  }

  // write bf16 partials: D row = quad*4+reg, col = lane&15
#pragma unroll
  for (int mi = 0; mi < 4; ++mi) {
    const int row0 = m0 + wm * 64 + mi * 16 + quad * 4;
#pragma unroll
    for (int ni = 0; ni < 4; ++ni) {
      const int col = n0 + wn * 64 + ni * 16 + lrow;
      unsigned short* pp = P + ((size_t)s * BB + row0) * CW + col;
#pragma unroll
      for (int r = 0; r < 4; ++r) pp[(size_t)r * CW] = f2bf(acc[mi][ni][r]);
    }
  }
}

// ---------------- K4: epilogue — sum bf16 split-K partials, cos/sin/relu, gated expert sum
__global__ void k_epi(const unsigned short* __restrict__ P, const float* __restrict__ gw,
                      const float* __restrict__ colbias, float* __restrict__ out) {
  const int b = blockIdx.x;
  const int r = threadIdx.x;            // 192: wave0 = wp cols, waves1-2 = wn cols
  __shared__ float gws[NEXP];
  if (r < NEXP) gws[r] = gw[b * NEXP + r];
  __syncthreads();
  float co = 0.f, si = 0.f, nc = 0.f;
  for (int n = 0; n < NEXP; ++n) {
    const int c = n * 192 + r;
    float v = colbias[c];
#pragma unroll
    for (int s2 = 0; s2 < NSPLIT; ++s2) v += bf2f(P[((size_t)s2 * BB + b) * CW + c]);
    const float g = gws[n];
    if (r < 64) { co = fmaf(g, cosf(v), co); si = fmaf(g, sinf(v), si); }
    else        { nc = fmaf(g, fmaxf(v, 0.f), nc); }
  }
  if (r < 64) { out[b * 256 + r] = co; out[b * 256 + 64 + r] = si; }
  else        { out[b * 256 + 128 + (r - 64)] = nc; }
}

extern "C" void kernel_launch(void* const* d_in, const int* in_sizes, int n_in,
                              void* d_out, int out_size, void* d_ws, size_t ws_size,
                              hipStream_t stream) {
  const float* x    = (const float*)d_in[0];
  const float* cond = (const float*)d_in[1];
  const float* bwp  = (const float*)d_in[2];
  const float* bwn  = (const float*)d_in[3];
  const float* bbn  = (const float*)d_in[4];
  const float* hW1  = (const float*)d_in[5];
  const float* hb1  = (const float*)d_in[6];
  const float* hW2  = (const float*)d_in[7];
  const float* hb2  = (const float*)d_in[8];
  const float* gW1  = (const float*)d_in[9];
  const float* gb1  = (const float*)d_in[10];
  const float* gW2  = (const float*)d_in[11];
  const float* gb2  = (const float*)d_in[12];
  float* out = (float*)d_out;
  char* ws = (char*)d_ws;

  unsigned short* Xb  = (unsigned short*)(ws + XB_OFF);
  unsigned short* Hbr = (unsigned short*)(ws + HBR_OFF);
  float* gw      = (float*)(ws + GW_OFF);
  float* colbias = (float*)(ws + CB_OFF);
  unsigned short* Bt = (unsigned short*)(ws + BT_OFF);
  unsigned short* Pp = (unsigned short*)(ws + P_OFF);

  hipLaunchKernelGGL(k_bt, dim3(2048), dim3(256), 0, stream,
                     hW2, Bt, bwp, bwn, bbn, hb2, colbias,
                     x, cond, hW1, hb1, gW1, gb1, gW2, gb2, Xb, Hbr, gw);
  hipLaunchKernelGGL(k_gemm, dim3(768), dim3(256), 0, stream, Xb, Hbr, Bt, Pp);
  hipLaunchKernelGGL(k_epi, dim3(BB), dim3(192), 0, stream, Pp, gw, colbias, out);
}

// Round 8
// 218.040 us; speedup vs baseline: 1.2416x; 1.2416x over previous
//
#include <hip/hip_runtime.h>
#include <math.h>

// Problem constants
#define BB     512
#define INF    256
#define CONDF  128
#define NEXP   8
#define HDIM   64
#define TPE    49280      // IN*DP + IN*DN + DN
#define TOTC   394240     // N*TPE
#define NSPLIT 16
#define CW     1536       // GEMM columns: 8 experts * (64 wp + 128 wn)
#define KB     261        // K blocks of 64: 64*4 main + 5 tail (16704 total K)

// Workspace layout (bytes). Total ~93.6 MB.
#define AZ_OFF 0u                     // ushort [261][512][64]  = 17,104,896
#define BT_OFF 17104896u              // ushort [261][1536][64] = 51,314,688
#define P_OFF  68419584u              // ushort [16][512][1536] = 25,165,824 (bf16 partials)
#define GW_OFF 93585408u              // float  [512][8]
#define CB_OFF 93601792u              // float  [1536]

typedef __bf16          bf16x8 __attribute__((ext_vector_type(8)));
typedef unsigned short  us8    __attribute__((ext_vector_type(8)));
typedef float           f32x4  __attribute__((ext_vector_type(4)));

__device__ __forceinline__ unsigned short f2bf(float f) {
  unsigned u = __builtin_bit_cast(unsigned, f);
  u += 0x7fffu + ((u >> 16) & 1u);           // RNE
  return (unsigned short)(u >> 16);
}
__device__ __forceinline__ float bf2f(unsigned short u) {
  return __builtin_bit_cast(float, ((unsigned)u) << 16);
}

__device__ __forceinline__ void gld16(const void* g, const void* l) {
  __builtin_amdgcn_global_load_lds(
      (const __attribute__((address_space(1))) unsigned int*)g,
      (__attribute__((address_space(3))) unsigned int*)l, 16, 0, 0);
}

// ---------------- K2 (merged): blocks 0..1535 = Bt transpose + tail + colbias;
//                 blocks 1536..2047 = per-sample prep (h, gates, Az rows).
// Bt[kb][c][ko] bf16, kb = t*4+ib, c = ne*192+r. One transpose block per (t, ne, sec).
// LDS transpose with octet XOR swizzle:
//   element (p, i) stored at Ls[p*256 + ((i&7) | (((i>>3) ^ (p&31)) << 3))]
// Az[kb][b][ko]: k = t*256+i -> z = h_t*x_i ; tail kb 256..259 = x, kb 260 = h.
__global__ void k_bt(const float* __restrict__ hW2, unsigned short* __restrict__ Bt,
                     const float* __restrict__ bwp, const float* __restrict__ bwn,
                     const float* __restrict__ bbn, const float* __restrict__ hb2,
                     float* __restrict__ colbias,
                     const float* __restrict__ x, const float* __restrict__ cond,
                     const float* __restrict__ hW1, const float* __restrict__ hb1,
                     const float* __restrict__ gW1, const float* __restrict__ gb1,
                     const float* __restrict__ gW2, const float* __restrict__ gb2,
                     unsigned short* __restrict__ Az, float* __restrict__ gw) {
  const int bx = blockIdx.x;
  const int tid = threadIdx.x;          // 256

  if (bx >= 1536) {                     // ---- prep path (one block per sample)
    const int b = bx - 1536;
    __shared__ float xs[INF], cs[CONDF], hs[HDIM], g1[24], ls[8], es[8];
    xs[tid] = x[b * INF + tid];
    if (tid < CONDF) cs[tid] = cond[b * CONDF + tid];
    __syncthreads();
    if (tid < HDIM) {
      float acc = hb1[tid];
      for (int q = 0; q < CONDF; ++q) acc = fmaf(cs[q], hW1[q * HDIM + tid], acc);
      hs[tid] = fmaxf(acc, 0.f);
    }
    if (tid >= 64 && tid < 88) {
      const int r = tid - 64;
      float acc = gb1[r];
      for (int q = 0; q < CONDF; ++q) acc = fmaf(cs[q], gW1[q * 24 + r], acc);
      g1[r] = fmaxf(acc, 0.f);
    }
    __syncthreads();
    if (tid < NEXP) {
      float acc = gb2[tid];
      for (int j = 0; j < 24; ++j) acc = fmaf(g1[j], gW2[j * NEXP + tid], acc);
      ls[tid] = acc;
    }
    __syncthreads();
    if (tid < NEXP) {
      float m = ls[0];
      for (int j = 1; j < NEXP; ++j) m = fmaxf(m, ls[j]);
      es[tid] = expf(ls[tid] - m);
    }
    __syncthreads();
    if (tid < NEXP) {
      float s = 0.f;
      for (int j = 0; j < NEXP; ++j) s += es[j];
      gw[b * NEXP + tid] = es[tid] / s;
    }
    // z writes: 8 t-groups x 32 i-octets
    const int t0 = tid >> 5, ig = tid & 31;
#pragma unroll
    for (int tt = 0; tt < 8; ++tt) {
      const int t = tt * 8 + t0;
      const float hv = hs[t];
      us8 o;
#pragma unroll
      for (int j = 0; j < 8; ++j) o[j] = f2bf(hv * xs[ig * 8 + j]);
      *(us8*)(Az + ((size_t)(t * 4 + (ig >> 3)) * BB + b) * 64 + (ig & 7) * 8) = o;
    }
    // tail rows: kb 256..259 = x, kb 260 = h
    Az[((size_t)(256 + (tid >> 6)) * BB + b) * 64 + (tid & 63)] = f2bf(xs[tid]);
    if (tid < HDIM) Az[((size_t)260 * BB + b) * 64 + tid] = f2bf(hs[tid]);
    return;
  }

  // ---- Bt transpose path
  const int t = bx / 24, rem = bx % 24, ne = rem / 3, sec = rem % 3;
  const size_t base = (size_t)t * TOTC + (size_t)ne * TPE + (sec ? 16384 : 0);
  const int dst  = sec ? 128 : 64;
  const int poff = (sec == 2) ? 64 : 0;
  const int cbase = ne * 192 + (sec == 0 ? 0 : (sec == 1 ? 64 : 128));
  __shared__ __align__(16) unsigned short Ls[64 * 256];   // [p][i-swizzled]
#pragma unroll
  for (int it = 0; it < 16; ++it) {
    const int f = it * 256 + tid;       // 4096 float4s: i = f>>4 in 0..255, p4 = (f&15)*4
    const int i = f >> 4, p4 = (f & 15) * 4;
    const int e = i >> 3, q = i & 7;
    f32x4 v = *(const f32x4*)(hW2 + base + (size_t)i * dst + poff + p4);
#pragma unroll
    for (int j = 0; j < 4; ++j) {
      const int p = p4 + j;
      Ls[(p << 8) + (((e ^ (p & 31)) << 3) | q)] = f2bf(v[j]);
    }
  }
  // merged tail rows (threads 0-63, c2 = bx): kb 256..260 = base weights/hb2/bias rows
  if (tid < 64) {
    const int c2 = bx, ne2 = c2 / 192, r2 = c2 % 192;
#pragma unroll
    for (int kb = 0; kb < 5; ++kb) {
      const int j = kb * 64 + tid;      // 0..320
      float v;
      if (j < 256) {
        const int i = j;
        if (r2 < 64) v = bwp[(ne2 * INF + i) * 64 + r2] + hb2[(size_t)ne2 * TPE + i * 64 + r2];
        else         v = bwn[(ne2 * INF + i) * 128 + (r2 - 64)] + hb2[(size_t)ne2 * TPE + 16384 + i * 128 + (r2 - 64)];
      } else {
        const int t2 = j - 256;
        v = (r2 < 64) ? 0.f : hW2[(size_t)t2 * TOTC + (size_t)ne2 * TPE + 49152 + (r2 - 64)];
      }
      Bt[((size_t)(256 + kb) * CW + c2) * 64 + tid] = f2bf(v);
    }
    if (tid == 0)
      colbias[c2] = (r2 < 64) ? 0.f
                  : bbn[ne2 * 128 + (r2 - 64)] + hb2[(size_t)ne2 * TPE + 49152 + (r2 - 64)];
  }
  __syncthreads();
#pragma unroll
  for (int it2 = 0; it2 < 8; ++it2) {
    const int of = it2 * 256 + tid;     // 2048 us8 outputs
    const int p = of >> 5, seg = of & 31, ib = seg >> 3, k8 = seg & 7;
    us8 o = *(const us8*)(&Ls[(p << 8) + ((seg ^ (p & 31)) << 3)]);
    *(us8*)(Bt + ((size_t)(t * 4 + ib) * CW + cbase + p) * 64 + k8 * 8) = o;
  }
}

// ---------------- K3: split-K MFMA GEMM. Block 128m x 128n, 768 blocks = 3/CU.
// 1-D grid with XCD co-location swizzle: the 4 m-blocks of each (nt,s) group get
// linear ids 8 apart (same id%8 -> same XCD) so Bt/Az tiles are L2-resident.
//   id = (g>>3)*32 + (g&7) + mt*8   where g = nt*16+s
// P partials stored bf16 (error budget: ~0.01/partial * sqrt(16) -> ~0.04 rms).
__launch_bounds__(256, 3)
__global__ void k_gemm(const unsigned short* __restrict__ Az,
                       const unsigned short* __restrict__ Bt,
                       unsigned short* __restrict__ P) {
  const int bid = blockIdx.x;           // 0..767
  const int g  = (bid >> 5) * 8 + (bid & 7);
  const int mt = (bid >> 3) & 3;
  const int nt = g >> 4;                // 0..11
  const int s  = g & 15;                // 0..15
  const int m0 = mt * 128, n0 = nt * 128;
  // balanced split-K: first 5 splits take 17 kbs, rest 16  (5*17 + 11*16 = 261)
  const int kb0 = s * 16 + (s < 5 ? s : 5);
  const int kb1 = kb0 + 16 + (s < 5 ? 1 : 0);
  const int tid = threadIdx.x;
  __shared__ __align__(16) unsigned short As[128 * 64];
  __shared__ __align__(16) unsigned short Bs[128 * 64];

  f32x4 acc[4][4];
#pragma unroll
  for (int mi = 0; mi < 4; ++mi)
#pragma unroll
    for (int ni = 0; ni < 4; ++ni) acc[mi][ni] = (f32x4){0.f, 0.f, 0.f, 0.f};

  const int wv = tid >> 6, lane = tid & 63;
  const int wm = wv >> 1, wn = wv & 1;
  const int lrow = lane & 15, quad = lane >> 4;
  const int srow = tid >> 3;            // 0..31
  const int sg0  = tid & 7;

  const unsigned short* ab = Az + ((size_t)kb0 * BB + m0) * 64;
  const unsigned short* bb = Bt + ((size_t)kb0 * CW + n0) * 64;

  for (int kb = kb0; kb < kb1; ++kb) {
#pragma unroll
    for (int it = 0; it < 4; ++it) {
      const int r = it * 32 + srow;
      const int ga = sg0 ^ (r & 7);
      const int ldsoff = __builtin_amdgcn_readfirstlane(it * 4096 + wv * 1024);
      gld16(ab + (size_t)r * 64 + ga * 8, (const char*)As + ldsoff);
      gld16(bb + (size_t)r * 64 + ga * 8, (const char*)Bs + ldsoff);
    }
    __syncthreads();
#pragma unroll
    for (int kh = 0; kh < 2; ++kh) {
      bf16x8 af[4], bfr[4];
#pragma unroll
      for (int mi = 0; mi < 4; ++mi) {
        const int r = wm * 64 + mi * 16 + lrow;
        const int ga = (kh * 4 + quad) ^ (r & 7);
        af[mi] = *(const bf16x8*)(As + r * 64 + ga * 8);
      }
#pragma unroll
      for (int ni = 0; ni < 4; ++ni) {
        const int r = wn * 64 + ni * 16 + lrow;
        const int ga = (kh * 4 + quad) ^ (r & 7);
        bfr[ni] = *(const bf16x8*)(Bs + r * 64 + ga * 8);
      }
#pragma unroll
      for (int mi = 0; mi < 4; ++mi)
#pragma unroll
        for (int ni = 0; ni < 4; ++ni)
          acc[mi][ni] = __builtin_amdgcn_mfma_f32_16x16x32_bf16(af[mi], bfr[ni], acc[mi][ni], 0, 0, 0);
    }
    __syncthreads();
    ab += (size_t)BB * 64;
    bb += (size_t)CW * 64;
  }

  // write bf16 partials: D row = quad*4+reg, col = lane&15
#pragma unroll
  for (int mi = 0; mi < 4; ++mi) {
    const int row0 = m0 + wm * 64 + mi * 16 + quad * 4;
#pragma unroll
    for (int ni = 0; ni < 4; ++ni) {
      const int col = n0 + wn * 64 + ni * 16 + lrow;
      unsigned short* pp = P + ((size_t)s * BB + row0) * CW + col;
#pragma unroll
      for (int r = 0; r < 4; ++r) pp[(size_t)r * CW] = f2bf(acc[mi][ni][r]);
    }
  }
}

// ---------------- K4: epilogue — sum bf16 split-K partials, cos/sin/relu, gated expert sum
__global__ void k_epi(const unsigned short* __restrict__ P, const float* __restrict__ gw,
                      const float* __restrict__ colbias, float* __restrict__ out) {
  const int b = blockIdx.x;
  const int r = threadIdx.x;            // 192: wave0 = wp cols, waves1-2 = wn cols
  __shared__ float gws[NEXP];
  if (r < NEXP) gws[r] = gw[b * NEXP + r];
  __syncthreads();
  float co = 0.f, si = 0.f, nc = 0.f;
  for (int n = 0; n < NEXP; ++n) {
    const int c = n * 192 + r;
    float v = colbias[c];
#pragma unroll
    for (int s2 = 0; s2 < NSPLIT; ++s2) v += bf2f(P[((size_t)s2 * BB + b) * CW + c]);
    const float g = gws[n];
    if (r < 64) { co = fmaf(g, cosf(v), co); si = fmaf(g, sinf(v), si); }
    else        { nc = fmaf(g, fmaxf(v, 0.f), nc); }
  }
  if (r < 64) { out[b * 256 + r] = co; out[b * 256 + 64 + r] = si; }
  else        { out[b * 256 + 128 + (r - 64)] = nc; }
}

extern "C" void kernel_launch(void* const* d_in, const int* in_sizes, int n_in,
                              void* d_out, int out_size, void* d_ws, size_t ws_size,
                              hipStream_t stream) {
  const float* x    = (const float*)d_in[0];
  const float* cond = (const float*)d_in[1];
  const float* bwp  = (const float*)d_in[2];
  const float* bwn  = (const float*)d_in[3];
  const float* bbn  = (const float*)d_in[4];
  const float* hW1  = (const float*)d_in[5];
  const float* hb1  = (const float*)d_in[6];
  const float* hW2  = (const float*)d_in[7];
  const float* hb2  = (const float*)d_in[8];
  const float* gW1  = (const float*)d_in[9];
  const float* gb1  = (const float*)d_in[10];
  const float* gW2  = (const float*)d_in[11];
  const float* gb2  = (const float*)d_in[12];
  float* out = (float*)d_out;
  char* ws = (char*)d_ws;

  unsigned short* Az = (unsigned short*)(ws + AZ_OFF);
  unsigned short* Bt = (unsigned short*)(ws + BT_OFF);
  unsigned short* Pp = (unsigned short*)(ws + P_OFF);
  float* gw      = (float*)(ws + GW_OFF);
  float* colbias = (float*)(ws + CB_OFF);

  hipLaunchKernelGGL(k_bt, dim3(2048), dim3(256), 0, stream,
                     hW2, Bt, bwp, bwn, bbn, hb2, colbias,
                     x, cond, hW1, hb1, gW1, gb1, gW2, gb2, Az, gw);
  hipLaunchKernelGGL(k_gemm, dim3(768), dim3(256), 0, stream, Az, Bt, Pp);
  hipLaunchKernelGGL(k_epi, dim3(BB), dim3(192), 0, stream, Pp, gw, colbias, out);
}